// Round 8
// baseline (404.568 us; speedup 1.0000x reference)
//
#include <hip/hip_runtime.h>

typedef _Float16 f16;
typedef _Float16 f16x8 __attribute__((ext_vector_type(8)));
typedef float f32x4 __attribute__((ext_vector_type(4)));

__device__ __forceinline__ void gload_lds16(const void* g, void* l) {
  __builtin_amdgcn_global_load_lds((const __attribute__((address_space(1))) void*)g,
                                   (__attribute__((address_space(3))) void*)l, 16, 0, 0);
}

__device__ __forceinline__ f32x4 mfma16(f16x8 a, f16x8 b, f32x4 c) {
  return __builtin_amdgcn_mfma_f32_16x16x32_f16(a, b, c, 0, 0, 0);
}

// ---------------- small prep kernels (unchanged) ----------------

__global__ void k_cvt(const float* __restrict__ src, f16* __restrict__ dst, int n8) {
  int i = blockIdx.x * 256 + threadIdx.x;
  if (i >= n8) return;
  const float4* s4 = reinterpret_cast<const float4*>(src) + (size_t)i * 2;
  float4 a = s4[0], b = s4[1];
  f16x8 v;
  v[0] = (f16)a.x; v[1] = (f16)a.y; v[2] = (f16)a.z; v[3] = (f16)a.w;
  v[4] = (f16)b.x; v[5] = (f16)b.y; v[6] = (f16)b.z; v[7] = (f16)b.w;
  *reinterpret_cast<f16x8*>(dst + (size_t)i * 8) = v;
}

__global__ void k_cvt_at(const float* __restrict__ A, f16* __restrict__ at) {
  __shared__ float t[64][65];
  int bi = blockIdx.x, br = blockIdx.y;
  int tx = threadIdx.x & 63, ty = threadIdx.x >> 6;
#pragma unroll
  for (int p = 0; p < 16; ++p) {
    int r = p * 4 + ty;
    t[r][tx] = A[(size_t)(br * 64 + r) * 4096 + bi * 64 + tx];
  }
  __syncthreads();
#pragma unroll
  for (int p = 0; p < 16; ++p) {
    int i = p * 4 + ty;
    at[(size_t)(bi * 64 + i) * 256 + br * 64 + tx] = (f16)t[tx][i];
  }
}

__device__ __forceinline__ void stage_tile_lin(const f16* __restrict__ g, size_t row0, int k0,
                                               int ldg, f16* s, int wid, int lane) {
#pragma unroll
  for (int t = 0; t < 4; ++t) {
    int c = (wid * 4 + t) * 64 + lane;
    const f16* gp = g + (row0 + (size_t)(c >> 3)) * (size_t)ldg + k0 + (c & 7) * 8;
    gload_lds16(gp, s + (wid * 4 + t) * 512);
  }
}

__global__ __launch_bounds__(256) void k_lora(const f16* __restrict__ bh,
                                              const f16* __restrict__ at,
                                              const float* __restrict__ base,
                                              f16* __restrict__ ch,
                                              float* __restrict__ partial) {
  __shared__ f16 sA[128 * 64];
  __shared__ f16 sB[128 * 64];
  __shared__ float ssum[2][128];
  int tid = threadIdx.x;
  int wid = tid >> 6, lane = tid & 63;
  int wm = wid >> 1, wn = wid & 1;
  int ln = lane & 15, q = lane >> 4;
  int bm = blockIdx.x >> 5, bn = blockIdx.x & 31;
  int brow = bm * 128, bcol = bn * 128;
  f32x4 acc[4][4] = {};
  for (int kt = 0; kt < 256; kt += 64) {
    __syncthreads();
    stage_tile_lin(bh, brow, kt, 256, sA, wid, lane);
    stage_tile_lin(at, bcol, kt, 256, sB, wid, lane);
    __syncthreads();
#pragma unroll
    for (int ks = 0; ks < 2; ++ks) {
      f16x8 af[4], bf[4];
#pragma unroll
      for (int mi = 0; mi < 4; ++mi)
        af[mi] = *reinterpret_cast<const f16x8*>(&sA[(wm * 64 + mi * 16 + ln) * 64 + ks * 32 + q * 8]);
#pragma unroll
      for (int ni = 0; ni < 4; ++ni)
        bf[ni] = *reinterpret_cast<const f16x8*>(&sB[(wn * 64 + ni * 16 + ln) * 64 + ks * 32 + q * 8]);
#pragma unroll
      for (int mi = 0; mi < 4; ++mi)
#pragma unroll
        for (int ni = 0; ni < 4; ++ni)
          acc[mi][ni] = mfma16(af[mi], bf[ni], acc[mi][ni]);
    }
  }
#pragma unroll
  for (int mi = 0; mi < 4; ++mi) {
#pragma unroll
    for (int j = 0; j < 4; ++j) {
      int row = brow + wm * 64 + mi * 16 + q * 4 + j;
      float s = 0.f;
#pragma unroll
      for (int ni = 0; ni < 4; ++ni) {
        int col = bcol + wn * 64 + ni * 16 + ln;
        float v = base[(size_t)row * 4096 + col] + 0.5f * acc[mi][ni][j];
        ch[(size_t)row * 4096 + col] = (f16)v;
        s += v * v;
      }
#pragma unroll
      for (int m = 1; m < 16; m <<= 1) s += __shfl_xor(s, m, 64);
      if (ln == 0) ssum[wn][wm * 64 + mi * 16 + q * 4 + j] = s;
    }
  }
  __syncthreads();
  if (tid < 128) {
    float p = ssum[0][tid] + ssum[1][tid];
    partial[(size_t)(brow + tid) * 32 + bn] = p;
  }
}

__global__ void k_scale(const float* __restrict__ partial, const float* __restrict__ mag,
                        const float* __restrict__ turk, float* __restrict__ scale) {
  int o = blockIdx.x * 256 + threadIdx.x;
  float s = 0.f;
#pragma unroll
  for (int c = 0; c < 32; ++c) s += partial[(size_t)o * 32 + c];
  scale[o] = mag[o] * turk[o] / (sqrtf(s) + 1e-8f);
}

// ---------------- 256x128 main GEMM, BK=32, 2-phase loop, 2 blocks/CU ----------------
// 4 waves (2M x 2N), per-wave output 128x64: acc[8][4], 32 MFMA + 12 ds_read_b128/tile.
// LDS 48 KiB (A 2x8192 f16, B 2x4096 f16) -> 2 blocks resident per CU: when one block
// drains lgkm/vmcnt/barrier, the other's waves feed the MFMA pipe (m97/m114 mechanism).
// LDS layout per row (32 f16): 4 slots x 8 f16, stored with slot ^= (row>>1)&3.
//   Read bank check: byte = row*64 + slot'*16 -> quad(16B) = (4*row + slot') & 7;
//   a frag's 16 rows with slot' = q8 ^ ((row>>1)&3) spread uniformly: 8 lanes/quad =
//   the b128 service minimum (no conflict). Stage side applies the same XOR to the
//   GLOBAL column (both-sides rule): LDS stays linear for global_load_lds.

__global__ __launch_bounds__(256, 2) void k_main(const f16* __restrict__ xh,
                                                 const f16* __restrict__ ch,
                                                 const float* __restrict__ scale,
                                                 const float* __restrict__ bias,
                                                 float* __restrict__ out) {
  __shared__ __align__(16) f16 sA[16384];   // 2 bufs x 256x32
  __shared__ __align__(16) f16 sB[8192];    // 2 bufs x 128x32
  int tid = threadIdx.x;
  int wid = tid >> 6, lane = tid & 63;
  int wm = wid >> 1, wn = wid & 1;          // 2M x 2N
  int ln = lane & 15, q8 = lane >> 4;       // q8 = k-slot 0..3 (8 f16 each)
  int sw8 = (q8 ^ ((ln >> 1) & 3)) * 8;     // swizzled slot offset (f16)

  int bid = blockIdx.x;                     // 1024 blocks, 1024 % 8 == 0
  int swz = (bid & 7) * 128 + (bid >> 3);   // XCD-aware, bijective
  int bm = swz >> 5, bn = swz & 31;         // 32 M-panels x 32 N-panels
  size_t brow = (size_t)bm * 256;
  int bcol = bn * 128;

  f32x4 acc[8][4] = {};

  // staging: A = 4 chunks/thread, B = 2 chunks/thread (16B chunks)
  // chunk c = l*256 + wid*64 + lane: row = c>>2, slot = lane&3
  int u = (lane >> 3) & 3;                  // (row>>1)&3, same for all l (l*64/2 % 4 == 0)
  int swcol = ((lane & 3) ^ u) * 8;         // pre-swizzled global column
  int rloc = wid * 16 + (lane >> 2);
  const f16* pa = xh + (brow + rloc) * 4096 + swcol;
  const f16* pb = ch + ((size_t)bcol + rloc) * 4096 + swcol;
  f16* dA0 = sA + wid * 512;                // wave-uniform LDS bases (chunk l stride 2048)
  f16* dB0 = sB + wid * 512;

  // prologue: stage tile 0 -> buf0; collective drain
#pragma unroll
  for (int l = 0; l < 4; ++l) gload_lds16(pa + l * 262144, dA0 + l * 2048);
#pragma unroll
  for (int l = 0; l < 2; ++l) gload_lds16(pb + l * 262144, dB0 + l * 2048);
  pa += 32; pb += 32;
  asm volatile("s_waitcnt vmcnt(0)");
  __builtin_amdgcn_s_barrier();

#define KTILE(CUR, S)                                                                        \
  {                                                                                          \
    const int NC = (CUR) ^ 1;                                                                \
    const f16* cA = sA + (CUR) * 8192;                                                       \
    const f16* cB = sB + (CUR) * 4096;                                                       \
    if (S) {                                                                                 \
      f16* dA = dA0 + NC * 8192;                                                             \
      f16* dB = dB0 + NC * 4096;                                                             \
      _Pragma("unroll")                                                                      \
      for (int l = 0; l < 4; ++l) gload_lds16(pa + l * 262144, dA + l * 2048);               \
      _Pragma("unroll")                                                                      \
      for (int l = 0; l < 2; ++l) gload_lds16(pb + l * 262144, dB + l * 2048);               \
      pa += 32; pb += 32;                                                                    \
    }                                                                                        \
    f16x8 af[8], bf[4];                                                                      \
    _Pragma("unroll")                                                                        \
    for (int f = 0; f < 8; ++f)                                                              \
      af[f] = *reinterpret_cast<const f16x8*>(cA + (wm * 128 + f * 16 + ln) * 32 + sw8);     \
    _Pragma("unroll")                                                                        \
    for (int n = 0; n < 4; ++n)                                                              \
      bf[n] = *reinterpret_cast<const f16x8*>(cB + (wn * 64 + n * 16 + ln) * 32 + sw8);      \
    asm volatile("s_waitcnt lgkmcnt(0)");                                                    \
    __builtin_amdgcn_sched_barrier(0);                                                       \
    __builtin_amdgcn_s_setprio(1);                                                           \
    _Pragma("unroll")                                                                        \
    for (int f = 0; f < 8; ++f)                                                              \
      _Pragma("unroll")                                                                      \
      for (int n = 0; n < 4; ++n) acc[f][n] = mfma16(af[f], bf[n], acc[f][n]);               \
    __builtin_amdgcn_s_setprio(0);                                                           \
    if (S) asm volatile("s_waitcnt vmcnt(0)");                                               \
    __builtin_amdgcn_s_barrier();                                                            \
  }

  for (int t = 0; t < 126; t += 2) {
    KTILE(0, 1)
    KTILE(1, 1)
  }
  KTILE(0, 1)   // t=126, stages t=127
  KTILE(1, 0)   // t=127, pure compute
#undef KTILE

  // epilogue: out = scale[col]*acc + bias[col]
#pragma unroll
  for (int n = 0; n < 4; ++n) {
    int col = bcol + wn * 64 + n * 16 + ln;
    float sc = scale[col], bs = bias[col];
#pragma unroll
    for (int f = 0; f < 8; ++f)
#pragma unroll
      for (int j = 0; j < 4; ++j) {
        size_t row = brow + wm * 128 + f * 16 + q8 * 4 + j;
        out[row * 4096 + col] = sc * acc[f][n][j] + bs;
      }
  }
}

extern "C" void kernel_launch(void* const* d_in, const int* in_sizes, int n_in,
                              void* d_out, int out_size, void* d_ws, size_t ws_size,
                              hipStream_t stream) {
  const float* x    = (const float*)d_in[0];
  const float* base = (const float*)d_in[1];
  const float* bias = (const float*)d_in[2];
  const float* lA   = (const float*)d_in[3];
  const float* lB   = (const float*)d_in[4];
  const float* mag  = (const float*)d_in[5];
  const float* turk = (const float*)d_in[6];
  float* out = (float*)d_out;
  char* ws = (char*)d_ws;

  f16*   xh      = (f16*)(ws);                        // 64 MiB
  f16*   ch      = (f16*)(ws + 67108864);             // 32 MiB
  f16*   at      = (f16*)(ws + 100663296);            //  2 MiB
  f16*   bh      = (f16*)(ws + 102760448);            //  2 MiB
  float* partial = (float*)(ws + 104857600);          // 512 KiB
  float* scale   = (float*)(ws + 105381888);          // 16 KiB

  k_cvt<<<16384, 256, 0, stream>>>(x, xh, 4194304);
  k_cvt<<<512, 256, 0, stream>>>(lB, bh, 131072);
  k_cvt_at<<<dim3(64, 4), 256, 0, stream>>>(lA, at);
  k_lora<<<1024, 256, 0, stream>>>(bh, at, base, ch, partial);
  k_scale<<<16, 256, 0, stream>>>(partial, mag, turk, scale);
  k_main<<<1024, 256, 0, stream>>>(xh, ch, scale, bias, out);
}

// Round 10
// 357.631 us; speedup vs baseline: 1.1312x; 1.1312x over previous
//
#include <hip/hip_runtime.h>

typedef _Float16 f16;
typedef _Float16 f16x8 __attribute__((ext_vector_type(8)));
typedef float f32x4 __attribute__((ext_vector_type(4)));

__device__ __forceinline__ void gload_lds16(const void* g, void* l) {
  __builtin_amdgcn_global_load_lds((const __attribute__((address_space(1))) void*)g,
                                   (__attribute__((address_space(3))) void*)l, 16, 0, 0);
}

__device__ __forceinline__ f32x4 mfma16(f16x8 a, f16x8 b, f32x4 c) {
  return __builtin_amdgcn_mfma_f32_16x16x32_f16(a, b, c, 0, 0, 0);
}

// ---------------- prep kernels ----------------

// fp32 -> f16, 16 elems/thread: 64B read + 32B write per lane
__global__ void k_cvt16(const float* __restrict__ src, f16* __restrict__ dst, int n16) {
  int i = blockIdx.x * 256 + threadIdx.x;
  if (i >= n16) return;
  const float4* s4 = reinterpret_cast<const float4*>(src) + (size_t)i * 4;
  float4 a = s4[0], b = s4[1], c = s4[2], d = s4[3];
  f16x8 v0, v1;
  v0[0] = (f16)a.x; v0[1] = (f16)a.y; v0[2] = (f16)a.z; v0[3] = (f16)a.w;
  v0[4] = (f16)b.x; v0[5] = (f16)b.y; v0[6] = (f16)b.z; v0[7] = (f16)b.w;
  v1[0] = (f16)c.x; v1[1] = (f16)c.y; v1[2] = (f16)c.z; v1[3] = (f16)c.w;
  v1[4] = (f16)d.x; v1[5] = (f16)d.y; v1[6] = (f16)d.z; v1[7] = (f16)d.w;
  f16* dp = dst + (size_t)i * 16;
  *reinterpret_cast<f16x8*>(dp) = v0;
  *reinterpret_cast<f16x8*>(dp + 8) = v1;
}

__global__ void k_cvt_at(const float* __restrict__ A, f16* __restrict__ at) {
  __shared__ float t[64][65];
  int bi = blockIdx.x, br = blockIdx.y;
  int tx = threadIdx.x & 63, ty = threadIdx.x >> 6;
#pragma unroll
  for (int p = 0; p < 16; ++p) {
    int r = p * 4 + ty;
    t[r][tx] = A[(size_t)(br * 64 + r) * 4096 + bi * 64 + tx];
  }
  __syncthreads();
#pragma unroll
  for (int p = 0; p < 16; ++p) {
    int i = p * 4 + ty;
    at[(size_t)(bi * 64 + i) * 256 + br * 64 + tx] = (f16)t[tx][i];
  }
}

__device__ __forceinline__ void stage_tile_lin(const f16* __restrict__ g, size_t row0, int k0,
                                               int ldg, f16* s, int wid, int lane) {
#pragma unroll
  for (int t = 0; t < 4; ++t) {
    int c = (wid * 4 + t) * 64 + lane;
    const f16* gp = g + (row0 + (size_t)(c >> 3)) * (size_t)ldg + k0 + (c & 7) * 8;
    gload_lds16(gp, s + (wid * 4 + t) * 512);
  }
}

__global__ __launch_bounds__(256) void k_lora(const f16* __restrict__ bh,
                                              const f16* __restrict__ at,
                                              const float* __restrict__ base,
                                              f16* __restrict__ ch,
                                              float* __restrict__ partial) {
  __shared__ f16 sA[128 * 64];
  __shared__ f16 sB[128 * 64];
  __shared__ float ssum[2][128];
  int tid = threadIdx.x;
  int wid = tid >> 6, lane = tid & 63;
  int wm = wid >> 1, wn = wid & 1;
  int ln = lane & 15, q = lane >> 4;
  int bm = blockIdx.x >> 5, bn = blockIdx.x & 31;
  int brow = bm * 128, bcol = bn * 128;
  f32x4 acc[4][4] = {};
  for (int kt = 0; kt < 256; kt += 64) {
    __syncthreads();
    stage_tile_lin(bh, brow, kt, 256, sA, wid, lane);
    stage_tile_lin(at, bcol, kt, 256, sB, wid, lane);
    __syncthreads();
#pragma unroll
    for (int ks = 0; ks < 2; ++ks) {
      f16x8 af[4], bf[4];
#pragma unroll
      for (int mi = 0; mi < 4; ++mi)
        af[mi] = *reinterpret_cast<const f16x8*>(&sA[(wm * 64 + mi * 16 + ln) * 64 + ks * 32 + q * 8]);
#pragma unroll
      for (int ni = 0; ni < 4; ++ni)
        bf[ni] = *reinterpret_cast<const f16x8*>(&sB[(wn * 64 + ni * 16 + ln) * 64 + ks * 32 + q * 8]);
#pragma unroll
      for (int mi = 0; mi < 4; ++mi)
#pragma unroll
        for (int ni = 0; ni < 4; ++ni)
          acc[mi][ni] = mfma16(af[mi], bf[ni], acc[mi][ni]);
    }
  }
#pragma unroll
  for (int mi = 0; mi < 4; ++mi) {
#pragma unroll
    for (int j = 0; j < 4; ++j) {
      int row = brow + wm * 64 + mi * 16 + q * 4 + j;
      float s = 0.f;
#pragma unroll
      for (int ni = 0; ni < 4; ++ni) {
        int col = bcol + wn * 64 + ni * 16 + ln;
        float v = base[(size_t)row * 4096 + col] + 0.5f * acc[mi][ni][j];
        ch[(size_t)row * 4096 + col] = (f16)v;
        s += v * v;
      }
#pragma unroll
      for (int m = 1; m < 16; m <<= 1) s += __shfl_xor(s, m, 64);
      if (ln == 0) ssum[wn][wm * 64 + mi * 16 + q * 4 + j] = s;
    }
  }
  __syncthreads();
  if (tid < 128) {
    float p = ssum[0][tid] + ssum[1][tid];
    partial[(size_t)(brow + tid) * 32 + bn] = p;
  }
}

__global__ void k_scale(const float* __restrict__ partial, const float* __restrict__ mag,
                        const float* __restrict__ turk, float* __restrict__ scale) {
  int o = blockIdx.x * 256 + threadIdx.x;
  float s = 0.f;
#pragma unroll
  for (int c = 0; c < 32; ++c) s += partial[(size_t)o * 32 + c];
  scale[o] = mag[o] * turk[o] / (sqrtf(s) + 1e-8f);
}

// ---------------- 256x256 8-phase main GEMM, R3 (proven 305us) verbatim ----------------
// Waves: 2M x 4N. Per-wave output 128x64. acc[8][4]. 24 ds_read_b128/wave/tile.
// LDS half = [128 rows][8 slots of 8 f16], slot stored XOR (row&7).

__device__ __forceinline__ void stage_half(const f16* __restrict__ g, size_t grow0, int gk0,
                                           f16* lbase, int wid, int lane) {
#pragma unroll
  for (int l = 0; l < 2; ++l) {
    int c = (wid * 2 + l) * 64 + lane;         // 0..1023
    int row = c >> 3, slot = c & 7;
    const f16* gp = g + (grow0 + row) * (size_t)4096 + gk0 + ((slot ^ (row & 7)) * 8);
    gload_lds16(gp, lbase + (wid * 2 + l) * 512);
  }
}

__device__ __forceinline__ void lda4(const f16* base, int g, int ln, int sw, f16x8 (&af)[4]) {
#pragma unroll
  for (int f = 0; f < 4; ++f)
    af[f] = *reinterpret_cast<const f16x8*>(base + (g * 64 + f * 16 + ln) * 64 + sw);
}

__device__ __forceinline__ void ldb4(const f16* base, int ln, int sw, f16x8 (&bf)[4]) {
#pragma unroll
  for (int n = 0; n < 4; ++n)
    bf[n] = *reinterpret_cast<const f16x8*>(base + (n * 16 + ln) * 64 + sw);
}

template <int G>
__device__ __forceinline__ void mfma16x(f16x8 (&af)[4], f16x8 (&bf)[4], f32x4 (&acc)[8][4]) {
#pragma unroll
  for (int f = 0; f < 4; ++f)
#pragma unroll
    for (int n = 0; n < 4; ++n)
      acc[G * 4 + f][n] = mfma16(af[f], bf[n], acc[G * 4 + f][n]);
}

__global__ __launch_bounds__(512, 2) void k_main(const f16* __restrict__ xh,
                                                 const f16* __restrict__ ch,
                                                 const float* __restrict__ scale,
                                                 const float* __restrict__ bias,
                                                 float* __restrict__ out) {
  __shared__ __align__(16) f16 sA[32768];   // 2 bufs x 2 halves x 128x64
  __shared__ __align__(16) f16 sB[32768];
  int tid = threadIdx.x;
  int wid = tid >> 6, lane = tid & 63;
  int wm = wid >> 2, wn = wid & 3;          // 2M x 4N
  int ln = lane & 15, q8 = lane >> 4;
  int sw0 = (q8 ^ (ln & 7)) * 8;
  int sw1 = ((4 + q8) ^ (ln & 7)) * 8;

  int bid = blockIdx.x;
  int swz = (bid & 7) * 64 + (bid >> 3);    // XCD-aware, bijective (512 % 8 == 0)
  int bm = swz >> 4, bn = swz & 15;
  size_t brow = (size_t)bm * 256;
  int bcol = bn * 256;

  f32x4 acc[8][4] = {};
  f16x8 af0[4], af1[4], af2[4], af3[4], bf0[4], bf1[4];

  const int aOff = wm * 8192;
  const int bOff = (wn >> 1) * 8192 + (wn & 1) * 4096;

  // prologue: t0 {Ah0,Ah1,Bh0,Bh1} -> buf0 ; t1 {Ah1,Ah0} -> buf1
  stage_half(xh, brow + 0,            0, sA + 0,            wid, lane);
  stage_half(xh, brow + 128,          0, sA + 8192,         wid, lane);
  stage_half(ch, (size_t)bcol + 0,    0, sB + 0,            wid, lane);
  stage_half(ch, (size_t)bcol + 128,  0, sB + 8192,         wid, lane);
  stage_half(xh, brow + 128,         64, sA + 16384 + 8192, wid, lane);
  stage_half(xh, brow + 0,           64, sA + 16384,        wid, lane);
  asm volatile("s_waitcnt vmcnt(4)");
  __builtin_amdgcn_s_barrier();

#define KTILE(CUR, T)                                                                      \
  {                                                                                        \
    const int NC = (CUR) ^ 1;                                                              \
    const f16* cA = sA + (CUR) * 16384 + aOff;                                             \
    const f16* cB = sB + (CUR) * 16384 + bOff;                                             \
    int t1 = (T) + 1; if (t1 > 63) t1 = 63;                                                \
    int t2 = (T) + 2; if (t2 > 63) t2 = 63;                                                \
    /* ph0: (g0,s0); stage t+1:Bh0 -> buf[NC] */                                           \
    lda4(cA, 0, ln, sw0, af0); ldb4(cB, ln, sw0, bf0);                                     \
    stage_half(ch, (size_t)bcol + 0, t1 * 64, sB + NC * 16384, wid, lane);                 \
    __builtin_amdgcn_s_barrier();                                                          \
    asm volatile("s_waitcnt lgkmcnt(0)");                                                  \
    __builtin_amdgcn_s_setprio(1); mfma16x<0>(af0, bf0, acc); __builtin_amdgcn_s_setprio(0); \
    __builtin_amdgcn_s_barrier();                                                          \
    /* ph1: (g0,s1); stage t+1:Bh1 -> buf[NC] */                                           \
    lda4(cA, 0, ln, sw1, af1); lda4(cA, 1, ln, sw0, af2); ldb4(cB, ln, sw1, bf1);          \
    stage_half(ch, (size_t)bcol + 128, t1 * 64, sB + NC * 16384 + 8192, wid, lane);        \
    asm volatile("s_waitcnt lgkmcnt(8)");                                                  \
    __builtin_amdgcn_s_barrier();                                                          \
    asm volatile("s_waitcnt lgkmcnt(0)");                                                  \
    __builtin_amdgcn_s_setprio(1); mfma16x<0>(af1, bf1, acc); __builtin_amdgcn_s_setprio(0); \
    __builtin_amdgcn_s_barrier();                                                          \
    /* ph2: (g1,s0); stage t+2:Ah1 -> buf[CUR] (A-h1 reads end this phase) */              \
    lda4(cA, 1, ln, sw1, af3);                                                             \
    stage_half(xh, brow + 128, t2 * 64, sA + (CUR) * 16384 + 8192, wid, lane);             \
    __builtin_amdgcn_s_barrier();                                                          \
    asm volatile("s_waitcnt lgkmcnt(0)");                                                  \
    __builtin_amdgcn_s_setprio(1); mfma16x<1>(af2, bf0, acc); __builtin_amdgcn_s_setprio(0); \
    __builtin_amdgcn_s_barrier();                                                          \
    /* ph3: (g1,s1); no ds_reads; stage t+2:Ah0 -> buf[CUR]; boundary vmcnt(4) */          \
    stage_half(xh, brow + 0, t2 * 64, sA + (CUR) * 16384, wid, lane);                      \
    __builtin_amdgcn_s_barrier();                                                          \
    __builtin_amdgcn_s_setprio(1); mfma16x<1>(af3, bf1, acc); __builtin_amdgcn_s_setprio(0); \
    asm volatile("s_waitcnt vmcnt(4)");                                                    \
    __builtin_amdgcn_s_barrier();                                                          \
  }

  for (int t = 0; t < 64; t += 2) {
    KTILE(0, t)
    KTILE(1, t + 1)
  }
#undef KTILE

  asm volatile("s_waitcnt vmcnt(0)");

  // epilogue: out = scale[col]*acc + bias[col]
#pragma unroll
  for (int n = 0; n < 4; ++n) {
    int col = bcol + wn * 64 + n * 16 + ln;
    float sc = scale[col], bs = bias[col];
#pragma unroll
    for (int mf = 0; mf < 8; ++mf)
#pragma unroll
      for (int j = 0; j < 4; ++j) {
        size_t row = brow + wm * 128 + mf * 16 + q8 * 4 + j;
        out[row * 4096 + col] = sc * acc[mf][n][j] + bs;
      }
  }
}

extern "C" void kernel_launch(void* const* d_in, const int* in_sizes, int n_in,
                              void* d_out, int out_size, void* d_ws, size_t ws_size,
                              hipStream_t stream) {
  const float* x    = (const float*)d_in[0];
  const float* base = (const float*)d_in[1];
  const float* bias = (const float*)d_in[2];
  const float* lA   = (const float*)d_in[3];
  const float* lB   = (const float*)d_in[4];
  const float* mag  = (const float*)d_in[5];
  const float* turk = (const float*)d_in[6];
  float* out = (float*)d_out;
  char* ws = (char*)d_ws;

  f16*   xh      = (f16*)(ws);                        // 64 MiB
  f16*   ch      = (f16*)(ws + 67108864);             // 32 MiB
  f16*   at      = (f16*)(ws + 100663296);            //  2 MiB
  f16*   bh      = (f16*)(ws + 102760448);            //  2 MiB
  float* partial = (float*)(ws + 104857600);          // 512 KiB
  float* scale   = (float*)(ws + 105381888);          // 16 KiB

  k_cvt16<<<8192, 256, 0, stream>>>(x, xh, 2097152);    // x -> f16 (33.5M elems)
  k_cvt16<<<256, 256, 0, stream>>>(lB, bh, 65536);      // lora_B -> f16 (1M elems)
  k_cvt_at<<<dim3(64, 4), 256, 0, stream>>>(lA, at);    // lora_A -> f16 transposed
  k_lora<<<1024, 256, 0, stream>>>(bh, at, base, ch, partial);
  k_scale<<<16, 256, 0, stream>>>(partial, mag, turk, scale);
  k_main<<<512, 512, 0, stream>>>(xh, ch, scale, bias, out);
}